// Round 2
// baseline (399.899 us; speedup 1.0000x reference)
//
#include <hip/hip_runtime.h>
#include <stdint.h>

// Problem constants (from reference)
#define N_CLASSES  10
#define N_TREES    4000
#define DEPTH      6
#define N_INTERNAL 63
#define N_FEATURES 128
#define BATCH      32768
#define LR         0.1f

// Kernel config.
// R14: 64 samples/block, lane==sample, trees WAVE-uniform (4 per wave per
// 16-tree tile -> 4 chains/thread). Depths 0-2 read their 7 top nodes via
// the SCALAR pipe (uniform s_load from pnodes) + v_cndmask selection, so the
// LDS pipe (the measured bottleneck: 12 b64 + 12 b32 per wave-tile ~= 614K
// cyc/CU ~= 243us) only serves depths 3-5: 12 b64 + 24 b32 per wave-tile
// covering 2x the (sample,tree) pairs -> ~0.87 cyc/pair vs 1.20.
#define BLOCK       256
#define SPB         64                      // samples per block (main kernel)
#define SAMPLES_PB  32                      // legacy geometry (fallback kernel)
#define T_TILE      16                      // trees per LDS tile (8 KB int2 nodes)
#define N_TILES     (N_TREES / T_TILE)      // 250
#define TILES_PER_CLASS ((N_TREES / N_CLASSES) / T_TILE)   // 25
#define SUMS_STRIDE 11

// prep grid split (unchanged geometry)
#define XPOSE_BLOCKS (BATCH / SAMPLES_PB)           // 1024
#define PACK_BLOCKS  ((N_TREES * 64) / BLOCK)       // 1000

// ws layout:
//   [0, 2.048MB)        nodes by slot, interleaved int2 (feat, thr_bits), 64/tree
//   [2.048MB, 3.072MB)  leaves (64 f32/tree), class-grouped slots
//   [3.072MB, 19.85MB)  x^T: [N_FEATURES][BATCH] f32 (DMA-friendly staging)
// slot = (t%10)*400 + t/10  (class-grouped: 25-tile runs are single-class).
#define WS_NODES_BYTES  ((size_t)N_TREES * 64 * 8)
#define WS_LEAVES_BYTES ((size_t)N_TREES * 64 * 4)
#define WS_XT_BYTES     ((size_t)N_FEATURES * BATCH * 4)

// s_waitcnt immediates (gfx9): vmcnt[3:0] | expcnt<<4 | lgkmcnt<<8
// Steady state in-flight at the wait: lv(t-1)[4] + DMA(t+1)[2] -> vmcnt(6)
// drains DMA(t). Last tile: keep lv[4] only -> vmcnt(4).
#define WAITCNT_VM6  0x0F76
#define WAITCNT_VM4  0x0F74

// Fused prep: blocks [0,1024) transpose x into x^T; blocks [1024,2024) pack
// nodes+leaves into class-grouped slots.
__global__ void prep_kernel(const float* __restrict__ x,
                            const int* __restrict__ features,
                            const float* __restrict__ thresholds,
                            const float* __restrict__ leaves,
                            int2* __restrict__ pn, float* __restrict__ pl,
                            float* __restrict__ xt) {
    const int tid = threadIdx.x;
    if (blockIdx.x < XPOSE_BLOCKS) {
        __shared__ float tile[N_FEATURES * 33];
        const int sample0 = blockIdx.x * SAMPLES_PB;
        const float4* xg = (const float4*)(x + (size_t)sample0 * N_FEATURES);
        #pragma unroll
        for (int k = 0; k < 4; ++k) {
            int e = tid + k * BLOCK;
            int s = e >> 5, f4 = e & 31;
            float4 v = xg[e];
            int f = f4 << 2;
            tile[(f + 0) * 33 + s] = v.x;
            tile[(f + 1) * 33 + s] = v.y;
            tile[(f + 2) * 33 + s] = v.z;
            tile[(f + 3) * 33 + s] = v.w;
        }
        __syncthreads();
        #pragma unroll
        for (int k = 0; k < 4; ++k) {
            int e = tid + k * BLOCK;
            int f = e >> 3, sq = e & 7;
            float4 w;
            w.x = tile[f * 33 + 4 * sq + 0];
            w.y = tile[f * 33 + 4 * sq + 1];
            w.z = tile[f * 33 + 4 * sq + 2];
            w.w = tile[f * 33 + 4 * sq + 3];
            *(float4*)(xt + (size_t)f * BATCH + sample0 + 4 * sq) = w;
        }
    } else {
        int i = (blockIdx.x - XPOSE_BLOCKS) * BLOCK + tid;
        int t = i >> 6, n = i & 63;
        int slot = (t % N_CLASSES) * (N_TREES / N_CLASSES) + (t / N_CLASSES);
        if (n < N_INTERNAL)
            pn[slot * 64 + n] = make_int2(features[t * N_INTERNAL + n],
                                          __float_as_int(thresholds[t * N_INTERNAL + n]));
        pl[slot * 64 + n] = leaves[t * 64 + n];
    }
}

// Standalone pack (mid tier without xt space)
__global__ void pack_kernel(const int* __restrict__ features,
                            const float* __restrict__ thresholds,
                            const float* __restrict__ leaves,
                            int2* __restrict__ pn, float* __restrict__ pl) {
    int i = blockIdx.x * blockDim.x + threadIdx.x;
    int t = i >> 6, n = i & 63;
    if (t < N_TREES) {
        int slot = (t % N_CLASSES) * (N_TREES / N_CLASSES) + (t / N_CLASSES);
        if (n < N_INTERNAL)
            pn[slot * 64 + n] = make_int2(features[t * N_INTERNAL + n],
                                          __float_as_int(thresholds[t * N_INTERNAL + n]));
        pl[slot * 64 + n] = leaves[t * 64 + n];
    }
}

// CK-style addrspace casts for global_load_lds (proven R5..R12).
__device__ __forceinline__ void load_lds_16(const void* g, void* l) {
    const auto* g1 = reinterpret_cast<const __attribute__((address_space(1))) uint32_t*>(
        reinterpret_cast<uintptr_t>(g));
    auto* l3 = reinterpret_cast<__attribute__((address_space(3))) uint32_t*>(
        reinterpret_cast<uintptr_t>(l));
    __builtin_amdgcn_global_load_lds(g1, l3, 16, 0, 0);
}

template <bool XT>
__global__ __launch_bounds__(BLOCK, 4) void gbt_eval(
    const float* __restrict__ x,        // original [BATCH][F] (XT=false path)
    const float* __restrict__ xt,       // x^T [F][BATCH]      (XT=true path)
    const int2*  __restrict__ pnodes,   // [N_TREES][64] int2, class-grouped slots
    const float* __restrict__ pleaves,  // [N_TREES][64], class-grouped slots
    const float* __restrict__ init_out, // [10]
    float*       __restrict__ out)      // [BATCH][10], written directly
{
    __shared__ float xs[N_FEATURES * SPB];              // 32 KB, transposed [f][s]
    __shared__ int2  nbuf[2][T_TILE * 64];              // 2 x 8 KB node tiles
    __shared__ float sums[SPB * SUMS_STRIDE];           // 2.8 KB

    const int tid  = threadIdx.x;
    const int lane = tid & 63;                          // lane == sample
    const int wvu  = __builtin_amdgcn_readfirstlane(tid >> 6);  // wave 0..3, provably uniform
    const int sample0 = blockIdx.x * SPB;

    if (XT) {
        // Stage xs[f][64]: wave wvu loads features [wvu*32, wvu*32+32).
        // Per chunk: 16 lanes cover one 256 B feature row -> 4 rows / 1 KB DMA.
        #pragma unroll
        for (int q = 0; q < 8; ++q) {
            int f0 = wvu * 32 + q * 4;
            const char* g = (const char*)(xt
                + (size_t)(f0 + (lane >> 4)) * BATCH + sample0 + (lane & 15) * 4);
            load_lds_16(g, (char*)xs + (size_t)f0 * SPB * 4);
        }
    } else {
        const float4* xg = (const float4*)(x + (size_t)sample0 * N_FEATURES);
        for (int e = tid; e < SPB * (N_FEATURES / 4); e += BLOCK) {
            int s = e >> 5, f4 = e & 31;
            float4 v = xg[e];
            int f = f4 << 2;
            xs[(f + 0) * SPB + s] = v.x;
            xs[(f + 1) * SPB + s] = v.y;
            xs[(f + 2) * SPB + s] = v.z;
            xs[(f + 3) * SPB + s] = v.w;
        }
    }
    for (int i = tid; i < SPB * SUMS_STRIDE; i += BLOCK) sums[i] = 0.f;

    // Stage one 8 KB int2 node tile. Wave wvu DMAs chunks 2wvu,2wvu+1 (trees
    // 4wvu..4wvu+3) -- exactly the trees its own lanes read: wave-private.
    auto stage = [&](int tile, int b) {
        const char* g = (const char*)(pnodes + (size_t)(tile * T_TILE) * 64);
        char* lbase = (char*)&nbuf[b][0];
        #pragma unroll
        for (int q = 0; q < 2; ++q) {
            int k = wvu * 2 + q;
            load_lds_16(g + k * 1024 + lane * 16, lbase + k * 1024);
        }
    };

    stage(0, 0);
    __syncthreads();   // xs is cross-wave shared: one full barrier (drains vmcnt)

    int cur = 0;
    for (int c = 0; c < N_CLASSES; ++c) {
        float acc = 0.f;
        float lv[4] = {0.f, 0.f, 0.f, 0.f};    // pipelined leaf loads (prev tile)
        for (int t25 = 0; t25 < TILES_PER_CLASS; ++t25) {
            const int tile = c * TILES_PER_CLASS + t25;
            const bool pre = (tile + 1 < N_TILES);
            if (pre) stage(tile + 1, cur ^ 1);

            // ---- Phase A: depths 0-2, node data from the SCALAR pipe ----
            // slot is wave-uniform -> tp[0..6] compile to s_load (no DS/VMEM
            // vector traffic). Selection among 2/4 candidates via cndmask.
            int o[4];
            #pragma unroll
            for (int u = 0; u < 4; ++u) {
                const int slot = tile * T_TILE + wvu * 4 + u;
                const int2* tp = pnodes + (size_t)slot * 64;
                int2 n0 = tp[0], n1 = tp[1], n2 = tp[2], n3 = tp[3];
                int2 n4 = tp[4], n5 = tp[5], n6 = tp[6];
                float x0 = xs[n0.x * SPB + lane];
                int b0 = x0 > __int_as_float(n0.y);
                int2 m1 = b0 ? n2 : n1;
                float x1 = xs[m1.x * SPB + lane];
                int b1 = x1 > __int_as_float(m1.y);
                int2 mA = b0 ? n5 : n3;
                int2 mB = b0 ? n6 : n4;
                int2 m2 = b1 ? mB : mA;
                float x2 = xs[m2.x * SPB + lane];
                int b2 = x2 > __int_as_float(m2.y);
                o[u] = 7 + 4 * b0 + 2 * b1 + b2;    // node index entering depth 3
            }

            // Wait for THIS tile's DMA only; phase A gave it a whole extra
            // phase of slack. FIFO: DMA(t) < lv(t-1)[4] < DMA(t+1)[2].
            // (builtin requires a literal constant -> two call sites)
            if (pre) {
                __builtin_amdgcn_s_waitcnt(WAITCNT_VM6);
            } else {
                __builtin_amdgcn_s_waitcnt(WAITCNT_VM4);
            }

            // ---- Phase B: depths 3-5, LDS gather (the only DS gathers left) --
            #pragma unroll
            for (int u = 0; u < 4; ++u) {
                const int2* nb = &nbuf[cur][(wvu * 4 + u) * 64];
                int oo = o[u];
                #pragma unroll
                for (int d = 3; d < DEPTH; ++d) {
                    int2 a = nb[oo];                // ds_read_b64
                    float xv = xs[a.x * SPB + lane];
                    oo = 2 * oo + 1 + (xv > __int_as_float(a.y) ? 1 : 0);
                }
                const size_t slot = (size_t)(tile * T_TILE + wvu * 4 + u);
                // Consume PREVIOUS tile's leaf (older than DMA(t+1): the
                // compiler's wait keeps the prefetch in flight), issue this one.
                acc += lv[u];
                lv[u] = pleaves[slot * 64 + (oo - N_INTERNAL)];
            }
            cur ^= 1;
        }
        acc += lv[0] + lv[1] + lv[2] + lv[3];   // flush the class's final quad
        atomicAdd(&sums[lane * SUMS_STRIDE + c], acc);
    }
    __syncthreads();

    // Sole owner of these samples: plain coalesced stores, init folded in.
    for (int e = tid; e < SPB * N_CLASSES; e += BLOCK) {
        int s = e / N_CLASSES, k = e - s * N_CLASSES;
        out[(size_t)(sample0 + s) * N_CLASSES + k] =
            init_out[k] + LR * sums[s * SUMS_STRIDE + k];
    }
}

// Fallback (ws too small even for nodes+leaves): direct-global gather,
// single block per 32 samples owns all trees (no atomics on out).
__global__ __launch_bounds__(BLOCK, 8) void gbt_eval_global(
    const float* __restrict__ x,
    const int*   __restrict__ features,
    const float* __restrict__ thresholds,
    const float* __restrict__ leaf_values,
    const float* __restrict__ init_out,
    float*       __restrict__ out)
{
    __shared__ float xs[N_FEATURES * SAMPLES_PB];
    __shared__ float sums[SAMPLES_PB * N_CLASSES];
    const int tid = threadIdx.x;
    const int sample0 = blockIdx.x * SAMPLES_PB;
    {
        const float4* xg = (const float4*)(x + (size_t)sample0 * N_FEATURES);
        for (int e = tid; e < SAMPLES_PB * (N_FEATURES / 4); e += BLOCK) {
            int s = e >> 5, f4 = e & 31;
            float4 v = xg[e];
            int f = f4 << 2;
            xs[(f + 0) * SAMPLES_PB + s] = v.x;
            xs[(f + 1) * SAMPLES_PB + s] = v.y;
            xs[(f + 2) * SAMPLES_PB + s] = v.z;
            xs[(f + 3) * SAMPLES_PB + s] = v.w;
        }
    }
    for (int i = tid; i < SAMPLES_PB * N_CLASSES; i += BLOCK) sums[i] = 0.f;
    __syncthreads();
    const int sLocal = tid & (SAMPLES_PB - 1);
    const int j = tid >> 5;
    const int TPT = N_TREES / 8;
    const int t0 = j * TPT;
    float acc[N_CLASSES];
    #pragma unroll
    for (int k = 0; k < N_CLASSES; ++k) acc[k] = 0.f;
    for (int i = 0; i < TPT; i += N_CLASSES) {
        const int tt = t0 + i;
        int idx[N_CLASSES];
        #pragma unroll
        for (int u = 0; u < N_CLASSES; ++u) idx[u] = 0;
        #pragma unroll
        for (int d = 0; d < DEPTH; ++d) {
            #pragma unroll
            for (int u = 0; u < N_CLASSES; ++u) {
                int base = (tt + u) * N_INTERNAL + idx[u];
                float xv = xs[features[base] * SAMPLES_PB + sLocal];
                idx[u] = 2 * idx[u] + 1 + (xv > thresholds[base] ? 1 : 0);
            }
        }
        #pragma unroll
        for (int u = 0; u < N_CLASSES; ++u)
            acc[u] += leaf_values[(size_t)(tt + u) * 64 + idx[u] - N_INTERNAL];
    }
    #pragma unroll
    for (int k = 0; k < N_CLASSES; ++k)
        atomicAdd(&sums[sLocal * N_CLASSES + k], acc[k]);
    __syncthreads();
    for (int e = tid; e < SAMPLES_PB * N_CLASSES; e += BLOCK) {
        int s = e / N_CLASSES, k = e - s * N_CLASSES;
        out[(size_t)(sample0 + s) * N_CLASSES + k] = init_out[k] + LR * sums[e];
    }
}

extern "C" void kernel_launch(void* const* d_in, const int* in_sizes, int n_in,
                              void* d_out, int out_size, void* d_ws, size_t ws_size,
                              hipStream_t stream) {
    const float* x          = (const float*)d_in[0];
    const int*   features   = (const int*)d_in[1];
    const float* thresholds = (const float*)d_in[2];
    const float* leafvals   = (const float*)d_in[3];
    const float* init_out   = (const float*)d_in[4];
    float*       out        = (float*)d_out;

    const int grid = BATCH / SPB;           // 512 = 256 CU x 2 blocks

    if (ws_size >= WS_NODES_BYTES + WS_LEAVES_BYTES + WS_XT_BYTES) {
        int2*  pn = (int2*)d_ws;
        float* pl = (float*)((char*)d_ws + WS_NODES_BYTES);
        float* xt = (float*)((char*)d_ws + WS_NODES_BYTES + WS_LEAVES_BYTES);
        prep_kernel<<<XPOSE_BLOCKS + PACK_BLOCKS, BLOCK, 0, stream>>>(
            x, features, thresholds, leafvals, pn, pl, xt);
        gbt_eval<true><<<grid, BLOCK, 0, stream>>>(x, xt, pn, pl, init_out, out);
    } else if (ws_size >= WS_NODES_BYTES + WS_LEAVES_BYTES) {
        int2*  pn = (int2*)d_ws;
        float* pl = (float*)((char*)d_ws + WS_NODES_BYTES);
        int n = N_TREES * 64;
        pack_kernel<<<(n + 255) / 256, 256, 0, stream>>>(features, thresholds,
                                                         leafvals, pn, pl);
        gbt_eval<false><<<grid, BLOCK, 0, stream>>>(x, nullptr, pn, pl, init_out, out);
    } else {
        gbt_eval_global<<<BATCH / SAMPLES_PB, BLOCK, 0, stream>>>(
            x, features, thresholds, leafvals, init_out, out);
    }
}